// Round 1
// 1620.017 us; speedup vs baseline: 1.2393x; 1.2393x over previous
//
#include <hip/hip_runtime.h>
#include <math.h>

// GCN_481036337415: 4-layer GCNConv (PyG norm w/ self-loops) + linear head.
// N=500000 nodes, E=16000000 edges. dims: 8 ->4 ->4 ->2 ->2 ->112.
//
// R1: device-scope f32 atomics ~20 G/s -> atomic scatter = 10.5 ms.
// R2: padded bucket-CSR via 16M int return-atomics + scattered 4B stores
//     (k_fill: 1010 us, WRITE_SIZE 988 MB = 64B granule per 4B store).
// R3 (this): kill k_fill. Two-pass WG binning into 977 dst-range buckets
//     (512 nodes each): LDS histograms + ONE global atomic per (WG,bucket)
//     (~478k atomics, 33x fewer), packed u32 entries (local_dst<<19 | src)
//     written in contiguous per-bucket runs (full-line evictions).
//     Gathers become per-bucket kernels: coalesced bin reads + random hin
//     gather + LDS accumulation (bank-conflict-padded) + coalesced finish.

constexpr int NN = 500000;
constexpr int NE = 16000000;

constexpr int BSH  = 9;                        // 512 nodes per bucket
constexpr int BNODES = 1 << BSH;               // 512
constexpr int NBK  = (NN + BNODES - 1) / BNODES;  // 977 buckets
constexpr int BCAP = 18432;                    // entries/bucket (mean 16384, +16 sigma)
constexpr int ECHUNK = 32768;                  // edges per binning WG
constexpr int NBA = (NE + ECHUNK - 1) / ECHUNK;   // 489 WGs

__device__ __forceinline__ void aadd(float* p, float v) {
    unsafeAtomicAdd(p, v);
}

// ======================= bucket-binned path =======================

__global__ __launch_bounds__(256) void k_tinit(int* __restrict__ tail) {
    int i = blockIdx.x * 256 + threadIdx.x;
    if (i < NBK) tail[i] = i * BCAP;
}

// Two-pass WG binning. Pass1: LDS bucket histogram. Reserve: one global
// atomicAdd per (WG,bucket). Pass2: LDS re-rank + packed write.
__global__ __launch_bounds__(256) void k_binA(const int* __restrict__ src,
                                              const int* __restrict__ dst,
                                              int* __restrict__ tail,
                                              unsigned* __restrict__ bins) {
    __shared__ int cnt[NBK];
    __shared__ int bbase[NBK];
    const int t = threadIdx.x;
    for (int k = t; k < NBK; k += 256) cnt[k] = 0;
    __syncthreads();

    const long e0 = (long)blockIdx.x * ECHUNK;
    const int ne = (int)min((long)ECHUNK, (long)NE - e0);  // 9216 for last WG
    const int g0 = (int)(e0 >> 2);
    const int ng = ne >> 2;  // NE%4==0 and chunk%4==0 -> exact

    // pass 1: count
    for (int g = t; g < ng; g += 256) {
        int4 d = ((const int4*)dst)[g0 + g];
        atomicAdd(&cnt[d.x >> BSH], 1);
        atomicAdd(&cnt[d.y >> BSH], 1);
        atomicAdd(&cnt[d.z >> BSH], 1);
        atomicAdd(&cnt[d.w >> BSH], 1);
    }
    __syncthreads();
    // reserve per-bucket ranges, reset counters for re-rank
    for (int k = t; k < NBK; k += 256) {
        int c = cnt[k];
        bbase[k] = c ? atomicAdd(&tail[k], c) : 0;
        cnt[k] = 0;
    }
    __syncthreads();
    // pass 2: re-rank + scatter packed entries (local_dst<<19 | src)
    for (int g = t; g < ng; g += 256) {
        int4 d = ((const int4*)dst)[g0 + g];
        int4 s = ((const int4*)src)[g0 + g];
        int b, r, idx;
        b = d.x >> BSH; r = atomicAdd(&cnt[b], 1); idx = bbase[b] + r;
        if (idx < (b + 1) * BCAP)
            bins[idx] = ((unsigned)(d.x & (BNODES - 1)) << 19) | (unsigned)s.x;
        b = d.y >> BSH; r = atomicAdd(&cnt[b], 1); idx = bbase[b] + r;
        if (idx < (b + 1) * BCAP)
            bins[idx] = ((unsigned)(d.y & (BNODES - 1)) << 19) | (unsigned)s.y;
        b = d.z >> BSH; r = atomicAdd(&cnt[b], 1); idx = bbase[b] + r;
        if (idx < (b + 1) * BCAP)
            bins[idx] = ((unsigned)(d.z & (BNODES - 1)) << 19) | (unsigned)s.z;
        b = d.w >> BSH; r = atomicAdd(&cnt[b], 1); idx = bbase[b] + r;
        if (idx < (b + 1) * BCAP)
            bins[idx] = ((unsigned)(d.w & (BNODES - 1)) << 19) | (unsigned)s.w;
    }
}

// Per-bucket degree count -> dinv (deg includes +1 self-loop).
__global__ __launch_bounds__(256) void k_deg(const unsigned* __restrict__ bins,
                                             const int* __restrict__ tail,
                                             float* __restrict__ dinv) {
    __shared__ int cnt[BNODES];
    const int b = blockIdx.x;
    const int t = threadIdx.x;
    cnt[t] = 0;
    cnt[t + 256] = 0;
    __syncthreads();
    const int base = b * BCAP;
    const int n = min(tail[b] - base, BCAP);
    const unsigned* e = bins + base;
    const int ng = n >> 2;
    for (int g = t; g < ng; g += 256) {
        uint4 v = ((const uint4*)e)[g];
        atomicAdd(&cnt[v.x >> 19], 1);
        atomicAdd(&cnt[v.y >> 19], 1);
        atomicAdd(&cnt[v.z >> 19], 1);
        atomicAdd(&cnt[v.w >> 19], 1);
    }
    for (int j = (ng << 2) + t; j < n; j += 256) atomicAdd(&cnt[e[j] >> 19], 1);
    __syncthreads();
    const int n0 = b << BSH;
    for (int r = t; r < BNODES; r += 256) {
        int node = n0 + r;
        if (node < NN) dinv[node] = rsqrtf((float)cnt[r] + 1.0f);
    }
}

// T1: hp = dinv * (x @ W1.T)
__global__ __launch_bounds__(256) void k_t1n(const float* __restrict__ x,
                                             const float* __restrict__ W,
                                             const float* __restrict__ dinv,
                                             float* __restrict__ hp) {
    int i = blockIdx.x * 256 + threadIdx.x;
    if (i >= NN) return;
    float4 x0 = ((const float4*)x)[2 * i];
    float4 x1 = ((const float4*)x)[2 * i + 1];
    float xi[8] = {x0.x, x0.y, x0.z, x0.w, x1.x, x1.y, x1.z, x1.w};
    float di = dinv[i];
    float o[4];
#pragma unroll
    for (int j = 0; j < 4; ++j) {
        float s = 0.f;
#pragma unroll
        for (int k = 0; k < 8; ++k) s = fmaf(xi[k], W[j * 8 + k], s);
        o[j] = di * s;
    }
    ((float4*)hp)[i] = make_float4(o[0], o[1], o[2], o[3]);
}

// Per-bucket gather: LDS accumulate hp[src], then finish conv (+self,+bias),
// activation, next-W transform, dinv prescale, coalesced write.
template <int IND, int OUTD, bool RELU>
__global__ __launch_bounds__(256) void g_buck(const unsigned* __restrict__ bins,
                                              const int* __restrict__ tail,
                                              const float* __restrict__ dinv,
                                              const float* __restrict__ hin,
                                              const float* __restrict__ bias,
                                              const float* __restrict__ Wn,
                                              float* __restrict__ hout) {
    constexpr int STR = (IND == 4) ? 5 : 3;  // pad stride vs 32 banks
    __shared__ float acc[BNODES * STR];
    const int b = blockIdx.x;
    const int t = threadIdx.x;
    for (int k = t; k < BNODES * STR; k += 256) acc[k] = 0.f;
    __syncthreads();
    const int base = b * BCAP;
    const int n = min(tail[b] - base, BCAP);
    const unsigned* e = bins + base;
    const int ng = n >> 2;
    for (int g = t; g < ng; g += 256) {
        uint4 v = ((const uint4*)e)[g];
        const unsigned s0 = v.x & 0x7FFFFu, l0 = v.x >> 19;
        const unsigned s1 = v.y & 0x7FFFFu, l1 = v.y >> 19;
        const unsigned s2 = v.z & 0x7FFFFu, l2 = v.z >> 19;
        const unsigned s3 = v.w & 0x7FFFFu, l3 = v.w >> 19;
        if constexpr (IND == 4) {
            float4 h0 = ((const float4*)hin)[s0];
            float4 h1 = ((const float4*)hin)[s1];
            float4 h2 = ((const float4*)hin)[s2];
            float4 h3 = ((const float4*)hin)[s3];
            atomicAdd(&acc[l0 * 5 + 0], h0.x); atomicAdd(&acc[l0 * 5 + 1], h0.y);
            atomicAdd(&acc[l0 * 5 + 2], h0.z); atomicAdd(&acc[l0 * 5 + 3], h0.w);
            atomicAdd(&acc[l1 * 5 + 0], h1.x); atomicAdd(&acc[l1 * 5 + 1], h1.y);
            atomicAdd(&acc[l1 * 5 + 2], h1.z); atomicAdd(&acc[l1 * 5 + 3], h1.w);
            atomicAdd(&acc[l2 * 5 + 0], h2.x); atomicAdd(&acc[l2 * 5 + 1], h2.y);
            atomicAdd(&acc[l2 * 5 + 2], h2.z); atomicAdd(&acc[l2 * 5 + 3], h2.w);
            atomicAdd(&acc[l3 * 5 + 0], h3.x); atomicAdd(&acc[l3 * 5 + 1], h3.y);
            atomicAdd(&acc[l3 * 5 + 2], h3.z); atomicAdd(&acc[l3 * 5 + 3], h3.w);
        } else {
            float2 h0 = ((const float2*)hin)[s0];
            float2 h1 = ((const float2*)hin)[s1];
            float2 h2 = ((const float2*)hin)[s2];
            float2 h3 = ((const float2*)hin)[s3];
            atomicAdd(&acc[l0 * 3 + 0], h0.x); atomicAdd(&acc[l0 * 3 + 1], h0.y);
            atomicAdd(&acc[l1 * 3 + 0], h1.x); atomicAdd(&acc[l1 * 3 + 1], h1.y);
            atomicAdd(&acc[l2 * 3 + 0], h2.x); atomicAdd(&acc[l2 * 3 + 1], h2.y);
            atomicAdd(&acc[l3 * 3 + 0], h3.x); atomicAdd(&acc[l3 * 3 + 1], h3.y);
        }
    }
    for (int j = (ng << 2) + t; j < n; j += 256) {
        unsigned v = e[j];
        const unsigned s0 = v & 0x7FFFFu, l0 = v >> 19;
        if constexpr (IND == 4) {
            float4 h0 = ((const float4*)hin)[s0];
            atomicAdd(&acc[l0 * 5 + 0], h0.x); atomicAdd(&acc[l0 * 5 + 1], h0.y);
            atomicAdd(&acc[l0 * 5 + 2], h0.z); atomicAdd(&acc[l0 * 5 + 3], h0.w);
        } else {
            float2 h0 = ((const float2*)hin)[s0];
            atomicAdd(&acc[l0 * 3 + 0], h0.x); atomicAdd(&acc[l0 * 3 + 1], h0.y);
        }
    }
    __syncthreads();
    const int n0 = b << BSH;
    for (int r = t; r < BNODES; r += 256) {
        const int node = n0 + r;
        if (node >= NN) continue;
        const float di = dinv[node];
        float h[IND];
        if constexpr (IND == 4) {
            float4 sv = ((const float4*)hin)[node];
            h[0] = di * (acc[r * 5 + 0] + sv.x) + bias[0];
            h[1] = di * (acc[r * 5 + 1] + sv.y) + bias[1];
            h[2] = di * (acc[r * 5 + 2] + sv.z) + bias[2];
            h[3] = di * (acc[r * 5 + 3] + sv.w) + bias[3];
        } else {
            float2 sv = ((const float2*)hin)[node];
            h[0] = di * (acc[r * 3 + 0] + sv.x) + bias[0];
            h[1] = di * (acc[r * 3 + 1] + sv.y) + bias[1];
        }
#pragma unroll
        for (int k = 0; k < IND; ++k) h[k] = RELU ? fmaxf(h[k], 0.f) : tanhf(h[k]);
        float o[OUTD];
#pragma unroll
        for (int q = 0; q < OUTD; ++q) {
            float s = 0.f;
#pragma unroll
            for (int k = 0; k < IND; ++k) s = fmaf(h[k], Wn[q * IND + k], s);
            o[q] = di * s;
        }
        if constexpr (OUTD == 4)
            ((float4*)hout)[node] = make_float4(o[0], o[1], o[2], o[3]);
        else
            ((float2*)hout)[node] = make_float2(o[0], o[1]);
    }
}

// Final per-bucket gather: finish conv4, tanh -> h[N,2] straight into out chunk.
__global__ __launch_bounds__(256) void g_fin(const unsigned* __restrict__ bins,
                                             const int* __restrict__ tail,
                                             const float* __restrict__ dinv,
                                             const float* __restrict__ hin,
                                             const float* __restrict__ b4,
                                             float* __restrict__ hout2) {
    __shared__ float acc[BNODES * 3];
    const int b = blockIdx.x;
    const int t = threadIdx.x;
    for (int k = t; k < BNODES * 3; k += 256) acc[k] = 0.f;
    __syncthreads();
    const int base = b * BCAP;
    const int n = min(tail[b] - base, BCAP);
    const unsigned* e = bins + base;
    const int ng = n >> 2;
    for (int g = t; g < ng; g += 256) {
        uint4 v = ((const uint4*)e)[g];
        const unsigned s0 = v.x & 0x7FFFFu, l0 = v.x >> 19;
        const unsigned s1 = v.y & 0x7FFFFu, l1 = v.y >> 19;
        const unsigned s2 = v.z & 0x7FFFFu, l2 = v.z >> 19;
        const unsigned s3 = v.w & 0x7FFFFu, l3 = v.w >> 19;
        float2 h0 = ((const float2*)hin)[s0];
        float2 h1 = ((const float2*)hin)[s1];
        float2 h2 = ((const float2*)hin)[s2];
        float2 h3 = ((const float2*)hin)[s3];
        atomicAdd(&acc[l0 * 3 + 0], h0.x); atomicAdd(&acc[l0 * 3 + 1], h0.y);
        atomicAdd(&acc[l1 * 3 + 0], h1.x); atomicAdd(&acc[l1 * 3 + 1], h1.y);
        atomicAdd(&acc[l2 * 3 + 0], h2.x); atomicAdd(&acc[l2 * 3 + 1], h2.y);
        atomicAdd(&acc[l3 * 3 + 0], h3.x); atomicAdd(&acc[l3 * 3 + 1], h3.y);
    }
    for (int j = (ng << 2) + t; j < n; j += 256) {
        unsigned v = e[j];
        const unsigned s0 = v & 0x7FFFFu, l0 = v >> 19;
        float2 h0 = ((const float2*)hin)[s0];
        atomicAdd(&acc[l0 * 3 + 0], h0.x); atomicAdd(&acc[l0 * 3 + 1], h0.y);
    }
    __syncthreads();
    const int n0 = b << BSH;
    for (int r = t; r < BNODES; r += 256) {
        const int node = n0 + r;
        if (node >= NN) continue;
        const float di = dinv[node];
        float2 sv = ((const float2*)hin)[node];
        float h0 = tanhf(di * (acc[r * 3 + 0] + sv.x) + b4[0]);
        float h1 = tanhf(di * (acc[r * 3 + 1] + sv.y) + b4[1]);
        ((float2*)hout2)[node] = make_float2(h0, h1);
    }
}

// Head: out[n,k] = h[n]·Wc[k] + bc[k]. One float4 (4 consecutive k) per thread.
__global__ __launch_bounds__(256) void k_f2(const float* __restrict__ h,
                                            const float* __restrict__ Wc,
                                            const float* __restrict__ bc,
                                            float* __restrict__ out) {
    int t = blockIdx.x * 256 + threadIdx.x;  // NN*28 units
    if (t >= NN * 28) return;
    int n = t / 28;
    int r = t - n * 28;
    int k = 4 * r;
    float2 hv = ((const float2*)h)[n];
    float4 o;
    o.x = fmaf(hv.y, Wc[2 * k + 1], fmaf(hv.x, Wc[2 * k + 0], bc[k + 0]));
    o.y = fmaf(hv.y, Wc[2 * k + 3], fmaf(hv.x, Wc[2 * k + 2], bc[k + 1]));
    o.z = fmaf(hv.y, Wc[2 * k + 5], fmaf(hv.x, Wc[2 * k + 4], bc[k + 2]));
    o.w = fmaf(hv.y, Wc[2 * k + 7], fmaf(hv.x, Wc[2 * k + 6], bc[k + 3]));
    ((float4*)out)[(size_t)n * 28 + r] = o;
}

// ================= fallback: R1 atomic-scatter path =================

__global__ __launch_bounds__(256) void k_init_deg(float* __restrict__ deg) {
    int i = blockIdx.x * 256 + threadIdx.x;
    if (i < NN) deg[i] = 1.0f;
}

__global__ __launch_bounds__(256) void k_count(const int* __restrict__ dst,
                                               float* __restrict__ deg) {
    int t = blockIdx.x * 256 + threadIdx.x;
    int4 d = ((const int4*)dst)[t];
    aadd(deg + d.x, 1.0f); aadd(deg + d.y, 1.0f);
    aadd(deg + d.z, 1.0f); aadd(deg + d.w, 1.0f);
}

__global__ __launch_bounds__(256) void k_dinv(float* __restrict__ deg) {
    int i = blockIdx.x * 256 + threadIdx.x;
    if (i < NN) deg[i] = 1.0f / sqrtf(deg[i]);
}

__global__ __launch_bounds__(256) void k_t1(const float* __restrict__ x,
                                            const float* __restrict__ W,
                                            const float* __restrict__ dinv,
                                            float* __restrict__ hp,
                                            float* __restrict__ ac) {
    int i = blockIdx.x * 256 + threadIdx.x;
    if (i >= NN) return;
    float4 x0 = ((const float4*)x)[2 * i];
    float4 x1 = ((const float4*)x)[2 * i + 1];
    float xi[8] = {x0.x, x0.y, x0.z, x0.w, x1.x, x1.y, x1.z, x1.w};
    float di = dinv[i];
    float o[4];
#pragma unroll
    for (int j = 0; j < 4; ++j) {
        float s = 0.f;
#pragma unroll
        for (int k = 0; k < 8; ++k) s = fmaf(xi[k], W[j * 8 + k], s);
        o[j] = di * s;
    }
    ((float4*)hp)[i] = make_float4(o[0], o[1], o[2], o[3]);
    ((float4*)ac)[i] = make_float4(0.f, 0.f, 0.f, 0.f);
}

__global__ __launch_bounds__(256) void k_s4(const int* __restrict__ src,
                                            const int* __restrict__ dst,
                                            const float* __restrict__ hp,
                                            float* __restrict__ ac) {
    int t = blockIdx.x * 256 + threadIdx.x;
    int4 s = ((const int4*)src)[t];
    int4 d = ((const int4*)dst)[t];
    float4 h;
    h = ((const float4*)hp)[s.x];
    aadd(ac + 4 * d.x + 0, h.x); aadd(ac + 4 * d.x + 1, h.y);
    aadd(ac + 4 * d.x + 2, h.z); aadd(ac + 4 * d.x + 3, h.w);
    h = ((const float4*)hp)[s.y];
    aadd(ac + 4 * d.y + 0, h.x); aadd(ac + 4 * d.y + 1, h.y);
    aadd(ac + 4 * d.y + 2, h.z); aadd(ac + 4 * d.y + 3, h.w);
    h = ((const float4*)hp)[s.z];
    aadd(ac + 4 * d.z + 0, h.x); aadd(ac + 4 * d.z + 1, h.y);
    aadd(ac + 4 * d.z + 2, h.z); aadd(ac + 4 * d.z + 3, h.w);
    h = ((const float4*)hp)[s.w];
    aadd(ac + 4 * d.w + 0, h.x); aadd(ac + 4 * d.w + 1, h.y);
    aadd(ac + 4 * d.w + 2, h.z); aadd(ac + 4 * d.w + 3, h.w);
}

__global__ __launch_bounds__(256) void k_s2(const int* __restrict__ src,
                                            const int* __restrict__ dst,
                                            const float* __restrict__ hp,
                                            float* __restrict__ ac) {
    int t = blockIdx.x * 256 + threadIdx.x;
    int4 s = ((const int4*)src)[t];
    int4 d = ((const int4*)dst)[t];
    float2 h;
    h = ((const float2*)hp)[s.x];
    aadd(ac + 2 * d.x + 0, h.x); aadd(ac + 2 * d.x + 1, h.y);
    h = ((const float2*)hp)[s.y];
    aadd(ac + 2 * d.y + 0, h.x); aadd(ac + 2 * d.y + 1, h.y);
    h = ((const float2*)hp)[s.z];
    aadd(ac + 2 * d.z + 0, h.x); aadd(ac + 2 * d.z + 1, h.y);
    h = ((const float2*)hp)[s.w];
    aadd(ac + 2 * d.w + 0, h.x); aadd(ac + 2 * d.w + 1, h.y);
}

template <bool RELU>
__global__ __launch_bounds__(256) void k_t44(const float* __restrict__ dinv,
                                             float* __restrict__ hp,
                                             float* __restrict__ ac,
                                             const float* __restrict__ bprev,
                                             const float* __restrict__ Wn) {
    int i = blockIdx.x * 256 + threadIdx.x;
    if (i >= NN) return;
    float di = dinv[i];
    float4 hv = ((const float4*)hp)[i];
    float4 av = ((const float4*)ac)[i];
    float h[4];
    h[0] = di * (av.x + hv.x) + bprev[0];
    h[1] = di * (av.y + hv.y) + bprev[1];
    h[2] = di * (av.z + hv.z) + bprev[2];
    h[3] = di * (av.w + hv.w) + bprev[3];
#pragma unroll
    for (int k = 0; k < 4; ++k) h[k] = RELU ? fmaxf(h[k], 0.f) : tanhf(h[k]);
    float o[4];
#pragma unroll
    for (int j = 0; j < 4; ++j) {
        float s = 0.f;
#pragma unroll
        for (int k = 0; k < 4; ++k) s = fmaf(h[k], Wn[j * 4 + k], s);
        o[j] = di * s;
    }
    ((float4*)hp)[i] = make_float4(o[0], o[1], o[2], o[3]);
    ((float4*)ac)[i] = make_float4(0.f, 0.f, 0.f, 0.f);
}

__global__ __launch_bounds__(256) void k_t42(const float* __restrict__ dinv,
                                             const float* __restrict__ hp4,
                                             const float* __restrict__ ac4,
                                             const float* __restrict__ bprev,
                                             const float* __restrict__ Wn,
                                             float* __restrict__ hp2,
                                             float* __restrict__ ac2) {
    int i = blockIdx.x * 256 + threadIdx.x;
    if (i >= NN) return;
    float di = dinv[i];
    float4 hv = ((const float4*)hp4)[i];
    float4 av = ((const float4*)ac4)[i];
    float h[4];
    h[0] = tanhf(di * (av.x + hv.x) + bprev[0]);
    h[1] = tanhf(di * (av.y + hv.y) + bprev[1]);
    h[2] = tanhf(di * (av.z + hv.z) + bprev[2]);
    h[3] = tanhf(di * (av.w + hv.w) + bprev[3]);
    float o0 = 0.f, o1 = 0.f;
#pragma unroll
    for (int k = 0; k < 4; ++k) {
        o0 = fmaf(h[k], Wn[k], o0);
        o1 = fmaf(h[k], Wn[4 + k], o1);
    }
    ((float2*)hp2)[i] = make_float2(di * o0, di * o1);
    ((float2*)ac2)[i] = make_float2(0.f, 0.f);
}

__global__ __launch_bounds__(256) void k_t22(const float* __restrict__ dinv,
                                             float* __restrict__ hp,
                                             float* __restrict__ ac,
                                             const float* __restrict__ bprev,
                                             const float* __restrict__ Wn) {
    int i = blockIdx.x * 256 + threadIdx.x;
    if (i >= NN) return;
    float di = dinv[i];
    float2 hv = ((const float2*)hp)[i];
    float2 av = ((const float2*)ac)[i];
    float h0 = fmaxf(di * (av.x + hv.x) + bprev[0], 0.f);
    float h1 = fmaxf(di * (av.y + hv.y) + bprev[1], 0.f);
    float o0 = fmaf(h1, Wn[1], h0 * Wn[0]);
    float o1 = fmaf(h1, Wn[3], h0 * Wn[2]);
    ((float2*)hp)[i] = make_float2(di * o0, di * o1);
    ((float2*)ac)[i] = make_float2(di * 0.f, di * 0.f);
}

__global__ __launch_bounds__(256) void k_f1(const float* __restrict__ dinv,
                                            const float* __restrict__ hp,
                                            float* __restrict__ ac,
                                            const float* __restrict__ b4,
                                            float* __restrict__ hout) {
    int i = blockIdx.x * 256 + threadIdx.x;
    if (i >= NN) return;
    float di = dinv[i];
    float2 hv = ((const float2*)hp)[i];
    float2 av = ((const float2*)ac)[i];
    float h0 = tanhf(di * (av.x + hv.x) + b4[0]);
    float h1 = tanhf(di * (av.y + hv.y) + b4[1]);
    ((float2*)hout)[i] = make_float2(h0, h1);
    ((float2*)ac)[i] = make_float2(h0, h1);
}

// ============================ launch ============================

extern "C" void kernel_launch(void* const* d_in, const int* in_sizes, int n_in,
                              void* d_out, int out_size, void* d_ws, size_t ws_size,
                              hipStream_t stream) {
    const float* x   = (const float*)d_in[0];
    const int*   ei  = (const int*)d_in[1];
    const int*   src = ei;
    const int*   dst = ei + NE;
    const float* W1 = (const float*)d_in[2];
    const float* b1 = (const float*)d_in[3];
    const float* W2 = (const float*)d_in[4];
    const float* b2 = (const float*)d_in[5];
    const float* W3 = (const float*)d_in[6];
    const float* b3 = (const float*)d_in[7];
    const float* W4 = (const float*)d_in[8];
    const float* b4 = (const float*)d_in[9];
    const float* Wc = (const float*)d_in[10];
    const float* bc = (const float*)d_in[11];
    float* out = (float*)d_out;
    float* hN2 = out + (size_t)112 * NN;   // second output chunk: h [N,2]

    const int NB_N  = (NN + 255) / 256;
    const int NB_E4 = NE / 4 / 256;        // 15625 exactly
    const int NB_F2 = (NN * 28 + 255) / 256;

    // new path workspace: 13N floats (dinv + ping-pong h) + tail + bins
    const size_t need_new = ((size_t)13 * NN + 1024 + (size_t)NBK * BCAP) * 4;  // ~98 MB

    if (ws_size >= need_new) {
        // ---- bucket-binned gather path ----
        float* ws   = (float*)d_ws;
        float* dinv = ws;                                  // N
        float* hpA  = ws + (size_t)NN;                     // 4N
        float* hpB  = ws + (size_t)5 * NN;                 // 4N
        float* h2A  = ws + (size_t)9 * NN;                 // 2N
        float* h2B  = ws + (size_t)11 * NN;                // 2N
        int*   tail = (int*)(ws + (size_t)13 * NN);        // NBK (pad 1024)
        unsigned* bins = (unsigned*)(ws + (size_t)13 * NN + 1024);  // NBK*BCAP

        k_tinit<<<(NBK + 255) / 256, 256, 0, stream>>>(tail);
        k_binA<<<NBA, 256, 0, stream>>>(src, dst, tail, bins);
        k_deg<<<NBK, 256, 0, stream>>>(bins, tail, dinv);
        k_t1n<<<NB_N, 256, 0, stream>>>(x, W1, dinv, hpA);
        // conv1 finish (relu,b1) + W2 transform
        g_buck<4, 4, true ><<<NBK, 256, 0, stream>>>(bins, tail, dinv, hpA, b1, W2, hpB);
        // conv2 finish (tanh,b2) + W3 transform
        g_buck<4, 2, false><<<NBK, 256, 0, stream>>>(bins, tail, dinv, hpB, b2, W3, h2A);
        // conv3 finish (relu,b3) + W4 transform
        g_buck<2, 2, true ><<<NBK, 256, 0, stream>>>(bins, tail, dinv, h2A, b3, W4, h2B);
        // conv4 finish (tanh,b4) -> h, straight into out chunk
        g_fin<<<NBK, 256, 0, stream>>>(bins, tail, dinv, h2B, b4, hN2);
        k_f2<<<NB_F2, 256, 0, stream>>>(hN2, Wc, bc, out);
    } else {
        // ---- fallback: R1 atomic-scatter path (passed @10.46 ms) ----
        float* ws   = (float*)d_ws;
        float* dinv = ws;
        float* hp4  = ws + (size_t)NN;
        float* ac4  = ws + (size_t)5 * NN;
        float* hp2  = ws + (size_t)9 * NN;
        float* ac2  = ws + (size_t)11 * NN;

        k_init_deg<<<NB_N, 256, 0, stream>>>(dinv);
        k_count<<<NB_E4, 256, 0, stream>>>(dst, dinv);
        k_dinv<<<NB_N, 256, 0, stream>>>(dinv);
        k_t1<<<NB_N, 256, 0, stream>>>(x, W1, dinv, hp4, ac4);
        k_s4<<<NB_E4, 256, 0, stream>>>(src, dst, hp4, ac4);
        k_t44<true><<<NB_N, 256, 0, stream>>>(dinv, hp4, ac4, b1, W2);
        k_s4<<<NB_E4, 256, 0, stream>>>(src, dst, hp4, ac4);
        k_t42<<<NB_N, 256, 0, stream>>>(dinv, hp4, ac4, b2, W3, hp2, ac2);
        k_s2<<<NB_E4, 256, 0, stream>>>(src, dst, hp2, ac2);
        k_t22<<<NB_N, 256, 0, stream>>>(dinv, hp2, ac2, b3, W4);
        k_s2<<<NB_E4, 256, 0, stream>>>(src, dst, hp2, ac2);
        k_f1<<<NB_N, 256, 0, stream>>>(dinv, hp2, ac2, b4, hN2);
        k_f2<<<NB_F2, 256, 0, stream>>>(ac2, Wc, bc, out);
    }
}